// Round 13
// baseline (1057.817 us; speedup 1.0000x reference)
//
#include <hip/hip_runtime.h>

#define NN 20000
#define EE 320000
#define DD 256
#define HH1 256
#define HH2 1024
#define CC1 4092
#define CC1P 4096
#define OUTC 10
#define EA (EE + NN)

#define CEILDIV(a,b) (((a)+(b)-1)/(b))

typedef unsigned short u16;
typedef __attribute__((ext_vector_type(8))) short bf16x8;
typedef __attribute__((ext_vector_type(4))) float f32x4;

__device__ __forceinline__ float b2f(unsigned short u) {
  union { unsigned int i; float f; } v; v.i = ((unsigned int)u) << 16; return v.f;
}
__device__ __forceinline__ unsigned short f2b(float f) {
  unsigned int x = __float_as_uint(f);
  unsigned int r = (x + 0x7fffu + ((x >> 16) & 1u)) >> 16;
  return (unsigned short)r;
}

// global -> LDS direct (16B/lane). LDS dest = wave-uniform base + lane*16.
__device__ __forceinline__ void gload16(const u16* g, u16* l) {
  __builtin_amdgcn_global_load_lds(
      (const __attribute__((address_space(1))) unsigned int*)(unsigned long long)(const void*)g,
      (__attribute__((address_space(3))) unsigned int*)(unsigned int)(unsigned long long)(void*)l,
      16, 0, 0);
}

// ---------------- utility ----------------
__global__ void k_zero32(unsigned int* __restrict__ p, int n) {
  int i = blockIdx.x * 256 + threadIdx.x;
  if (i < n) p[i] = 0u;
}

__global__ void k_f32_to_bf16(const float* __restrict__ in, u16* __restrict__ out, int n) {
  int i = blockIdx.x * 256 + threadIdx.x;
  if (i < n) out[i] = f2b(in[i]);
}

// convert + transpose: W[K][N] f32 -> out[N][Kp] bf16, zero-filled for k in [K,Kp)
__global__ void k_convT(const float* __restrict__ in, u16* __restrict__ out,
                        int K, int N, int Kp) {
  __shared__ float tile[32][33];
  int kb = blockIdx.y * 32, nb = blockIdx.x * 32;
  int tx = threadIdx.x & 31, ty = threadIdx.x >> 5;  // ty 0..7
  #pragma unroll
  for (int i = 0; i < 32; i += 8) {
    int k = kb + ty + i, n = nb + tx;
    tile[ty + i][tx] = (k < K && n < N) ? in[(size_t)k * N + n] : 0.f;
  }
  __syncthreads();
  #pragma unroll
  for (int i = 0; i < 32; i += 8) {
    int n = nb + ty + i, k = kb + tx;
    if (n < N && k < Kp) out[(size_t)n * Kp + k] = f2b(tile[tx][ty + i]);
  }
}

// ---------------- edge dtype detection (int32 vs int64 storage) ----------------
__global__ void k_detect_e64(const int* __restrict__ ei, int* __restrict__ flag) {
  __shared__ int nz;
  if (threadIdx.x == 0) nz = 0;
  __syncthreads();
  if (ei[2 * threadIdx.x + 1] != 0) atomicOr(&nz, 1);
  __syncthreads();
  if (threadIdx.x == 0) *flag = (nz == 0) ? 1 : 0;
}

__device__ __forceinline__ int eread(const int* __restrict__ ei, int f64, int idx) {
  return f64 ? ei[(size_t)idx * 2] : ei[idx];
}

// ---------------- projected attention vectors: one wave per output row ----------------
__global__ void k_proj_vec(const float* __restrict__ Ws, const float* __restrict__ as_,
                           const float* __restrict__ Wd, const float* __restrict__ ad_,
                           float* __restrict__ ps, float* __restrict__ pd, int K, int F) {
  int k = blockIdx.x;
  if (k >= K) return;
  int lane = threadIdx.x;  // 64
  const float* wsr = Ws + (size_t)k * F;
  const float* wdr = Wd + (size_t)k * F;
  float s = 0.f, d = 0.f;
  for (int f = lane * 4; f < F; f += 256) {
    float4 w1 = *(const float4*)(wsr + f);
    float4 a1 = *(const float4*)(as_ + f);
    float4 w2 = *(const float4*)(wdr + f);
    float4 a2 = *(const float4*)(ad_ + f);
    s += w1.x * a1.x + w1.y * a1.y + w1.z * a1.z + w1.w * a1.w;
    d += w2.x * a2.x + w2.y * a2.y + w2.z * a2.z + w2.w * a2.w;
  }
  #pragma unroll
  for (int off = 32; off > 0; off >>= 1) {
    s += __shfl_xor(s, off);
    d += __shfl_xor(d, off);
  }
  if (lane == 0) { ps[k] = s; pd[k] = d; }
}

// ---------------- per-node attention logits ----------------
__global__ void k_attn_logits(const u16* __restrict__ act, const float* __restrict__ ps,
                              const float* __restrict__ pd, float* __restrict__ als,
                              float* __restrict__ ald, int K) {
  int n = blockIdx.x;
  int lane = threadIdx.x;
  const u16* row = act + (size_t)n * K;
  float s = 0.f, d = 0.f;
  for (int k = lane; k < K; k += 64) {
    float v = b2f(row[k]);
    s += v * ps[k]; d += v * pd[k];
  }
  #pragma unroll
  for (int off = 32; off > 0; off >>= 1) { s += __shfl_down(s, off); d += __shfl_down(d, off); }
  if (lane == 0) { als[n] = s; ald[n] = d; }
}

// ---------------- CSR build (round-3 exact: single-block scan) ----------------
__global__ void k_edge_count(const int* __restrict__ ei, const int* __restrict__ eflag,
                             int* __restrict__ counts) {
  int k = blockIdx.x * 256 + threadIdx.x;
  if (k >= EA) return;
  int f64 = *eflag;
  int dst = (k < EE) ? eread(ei, f64, EE + k) : (k - EE);
  if ((unsigned)dst < (unsigned)NN) atomicAdd(&counts[dst], 1);
}

__global__ void k_scan(const int* __restrict__ counts, int* __restrict__ rowptr,
                       int* __restrict__ cursor, int n) {
  __shared__ int sdata[1024];
  __shared__ int s_carry;
  if (threadIdx.x == 0) s_carry = 0;
  __syncthreads();
  for (int base = 0; base < n; base += 1024) {
    int idx = base + threadIdx.x;
    int v = (idx < n) ? counts[idx] : 0;
    sdata[threadIdx.x] = v;
    __syncthreads();
    for (int off = 1; off < 1024; off <<= 1) {
      int t = (threadIdx.x >= off) ? sdata[threadIdx.x - off] : 0;
      __syncthreads();
      sdata[threadIdx.x] += t;
      __syncthreads();
    }
    int incl = sdata[threadIdx.x];
    int carry = s_carry;
    if (idx < n) { int e = carry + incl - v; rowptr[idx] = e; cursor[idx] = e; }
    __syncthreads();
    if (threadIdx.x == 1023) s_carry = carry + sdata[1023];
    __syncthreads();
  }
  if (threadIdx.x == 0) rowptr[n] = s_carry;
}

__global__ void k_edge_fill(const int* __restrict__ ei, const int* __restrict__ eflag,
                            int* __restrict__ cursor, int* __restrict__ esrc) {
  int k = blockIdx.x * 256 + threadIdx.x;
  if (k >= EA) return;
  int f64 = *eflag;
  int src, dst;
  if (k < EE) { src = eread(ei, f64, k); dst = eread(ei, f64, EE + k); }
  else { src = dst = k - EE; }
  if ((unsigned)dst >= (unsigned)NN) return;
  if ((unsigned)src >= (unsigned)NN) src = 0;
  int pos = atomicAdd(&cursor[dst], 1);
  esrc[pos] = src;
}

// ---------------- GAT aggregation: wave-parallel softmax + chunked LDS alpha ----------
#define ACHUNK 512
template<int FPT>
__global__ __launch_bounds__(256) void k_gat_aggregate(
    const int* __restrict__ rowptr, const int* __restrict__ esrc,
    const float* __restrict__ als, const float* __restrict__ ald,
    const u16* __restrict__ xs, const float* __restrict__ bias,
    u16* __restrict__ h, int F) {
  __shared__ float red[256];
  __shared__ float salpha[ACHUNK];
  __shared__ int   ssrc[ACHUNK];
  int n = blockIdx.x;
  int tid = threadIdx.x;
  int beg = rowptr[n], end = rowptr[n + 1];
  float ad = ald[n];

  // phase A: block-parallel max
  float m = -1e30f;
  for (int j = beg + tid; j < end; j += 256) {
    float e = als[esrc[j]] + ad; e = (e < 0.f) ? 0.2f * e : e;
    m = fmaxf(m, e);
  }
  red[tid] = m; __syncthreads();
  #pragma unroll
  for (int s = 128; s > 0; s >>= 1) {
    if (tid < s) red[tid] = fmaxf(red[tid], red[tid + s]);
    __syncthreads();
  }
  m = red[0]; __syncthreads();

  // phase B: block-parallel sum of exp
  float ss = 0.f;
  for (int j = beg + tid; j < end; j += 256) {
    float e = als[esrc[j]] + ad; e = (e < 0.f) ? 0.2f * e : e;
    ss += expf(e - m);
  }
  red[tid] = ss; __syncthreads();
  #pragma unroll
  for (int s = 128; s > 0; s >>= 1) {
    if (tid < s) red[tid] += red[tid + s];
    __syncthreads();
  }
  float inv = 1.f / (red[0] + 1e-16f); __syncthreads();

  // phase C: chunked alpha into LDS, then gather-FMA
  float acc[FPT];
  #pragma unroll
  for (int i = 0; i < FPT; ++i) acc[i] = 0.f;
  int fbase = tid * FPT;
  for (int cbeg = beg; cbeg < end; cbeg += ACHUNK) {
    int cend = min(cbeg + ACHUNK, end);
    for (int j = cbeg + tid; j < cend; j += 256) {
      int s = esrc[j];
      float e = als[s] + ad; e = (e < 0.f) ? 0.2f * e : e;
      salpha[j - cbeg] = expf(e - m) * inv;
      ssrc[j - cbeg] = s;
    }
    __syncthreads();
    int cn = cend - cbeg;
    for (int j = 0; j < cn; ++j) {
      float a = salpha[j];
      const u16* rowp = xs + (size_t)ssrc[j] * F + fbase;
      if (FPT == 4) {
        ushort4 v4 = *(const ushort4*)rowp;
        acc[0] += a * b2f(v4.x);
        acc[1] += a * b2f(v4.y);
        acc[2] += a * b2f(v4.z);
        acc[3] += a * b2f(v4.w);
      } else {
        acc[0] += a * b2f(rowp[0]);
      }
    }
    __syncthreads();
  }
  #pragma unroll
  for (int i = 0; i < FPT; ++i) {
    int f = fbase + i;
    float v = acc[i] + bias[f];
    h[(size_t)n * F + f] = f2b(v > 0.f ? v : 0.f);
  }
}

// ---------------- MFMA GEMM: 128x128, 3-deep pipeline with COUNTED vmcnt(16) ----
// T4: stage(t+2) stays in flight across the barrier; vmcnt(16) waits only for
// stage(t+1) (16 loads/wave per stage). Never drains to 0 in steady state.
// NT C-stores for STATS GEMMs: big C write streams (h3 163MB) were evicting the
// B panel from L3 -> 5.7x HBM over-fetch on FC1.
template<bool BIAS, bool STATS>
__global__ __launch_bounds__(256, 2) void k_mfma_gemm(
    const u16* __restrict__ A, const u16* __restrict__ Bt,
    const float* __restrict__ bias, u16* __restrict__ C,
    int M, int N, int K, int ldc, int nbx,
    float* __restrict__ bsum, float* __restrict__ bsumsq) {
  __shared__ u16 lds[24576];  // 3 buffers x (A 8KB + B 8KB) = 48 KB
  int tid = threadIdx.x;
  int lane = tid & 63;
  int w = tid >> 6;                 // wave 0..3; (w>>1, w&1) = 2x2 wave grid

  // bijective XCD band swizzle (m204)
  int nwg = gridDim.x;
  int id = blockIdx.x;
  int q = nwg >> 3, r = nwg & 7;
  int xcd = id & 7, pos = id >> 3;
  int swz = (xcd < r ? xcd * (q + 1) : r * (q + 1) + (xcd - r) * q) + pos;
  int m0 = (swz / nbx) * 128, n0 = (swz % nbx) * 128;

  int dr = lane >> 2;                          // dest row within 16-row chunk
  int ss = (lane & 3) ^ ((lane >> 3) & 3);     // inverse-swizzled source slot
  int lrow = lane & 15;                        // fragment row/col
  int lk = lane >> 4;                          // k-group 0..3

  f32x4 acc[4][4] = {};
  int c0 = w * 4;

  auto STAGE = [&](int k0, int bufb) {
    #pragma unroll
    for (int j = 0; j < 4; ++j) {
      int c = c0 + j;                 // chunk 0..15; 0..7 = A, 8..15 = B
      int tr = ((c & 7) << 4) + dr;   // tile row
      const u16* src;
      if (c < 8) {
        int rr = m0 + tr; rr = (rr < M) ? rr : (M - 1);
        src = A + (size_t)rr * K + k0 + ss * 8;
      } else {
        int rr = n0 + tr; rr = (rr < N) ? rr : (N - 1);
        src = Bt + (size_t)rr * K + k0 + ss * 8;
      }
      gload16(src, (u16*)((char*)lds + bufb + c * 1024));
    }
  };
  auto COMPUTE = [&](int bufb) {
    bf16x8 af[4], bfr[4];
    #pragma unroll
    for (int m = 0; m < 4; ++m) {
      int row = ((w >> 1) << 6) + m * 16 + lrow;
      af[m] = *(const bf16x8*)((const char*)lds + bufb + row * 64 +
                               ((lk ^ ((row >> 1) & 3)) << 4));
    }
    #pragma unroll
    for (int n = 0; n < 4; ++n) {
      int row = ((w & 1) << 6) + n * 16 + lrow;
      bfr[n] = *(const bf16x8*)((const char*)lds + bufb + 8192 + row * 64 +
                                ((lk ^ ((row >> 1) & 3)) << 4));
    }
    #pragma unroll
    for (int m = 0; m < 4; ++m)
      #pragma unroll
      for (int n = 0; n < 4; ++n)
        acc[m][n] = __builtin_amdgcn_mfma_f32_16x16x32_bf16(af[m], bfr[n], acc[m][n], 0, 0, 0);
  };

  // 3-deep pipeline. Each STAGE = 16 loads/wave. K is a multiple of 32, K/32 >= 2.
  int ntk = K >> 5;  // number of K-tiles
  STAGE(0, 0);
  if (ntk > 1) STAGE(32, 16384);
  asm volatile("s_waitcnt vmcnt(16)" ::: "memory");  // stage(0) landed
  __syncthreads();
  for (int t = 0; t < ntk; ++t) {
    int cb = (t % 3) * 16384;
    if (t + 2 < ntk) {
      STAGE((t + 2) * 32, ((t + 2) % 3) * 16384);
      COMPUTE(cb);
      asm volatile("s_waitcnt vmcnt(16)" ::: "memory");  // stage(t+1) landed
    } else {
      COMPUTE(cb);
      asm volatile("s_waitcnt vmcnt(0)" ::: "memory");   // drain tail
    }
    __syncthreads();
  }

  // epilogue: C write (+bias) and optional fused column stats
  int wrb = (w >> 1) * 64, wcb = (w & 1) * 64;
  float colS[4] = {0.f, 0.f, 0.f, 0.f}, colS2[4] = {0.f, 0.f, 0.f, 0.f};
  #pragma unroll
  for (int m = 0; m < 4; ++m) {
    #pragma unroll
    for (int qq = 0; qq < 4; ++qq) {
      int gm = m0 + wrb + m * 16 + lk * 4 + qq;  // C/D: row=(lane>>4)*4+reg
      bool okm = gm < M;
      #pragma unroll
      for (int n = 0; n < 4; ++n) {
        int gn = n0 + wcb + n * 16 + lrow;       // C/D: col=lane&15
        if (gn >= N) continue;
        float v = acc[m][n][qq];
        if (BIAS) v += bias[gn];
        if (okm) {
          u16 bv = f2b(v);
          if (STATS) {
            __builtin_nontemporal_store(bv, &C[(size_t)gm * ldc + gn]);
            colS[n] += v; colS2[n] += v * v;
          } else {
            C[(size_t)gm * ldc + gn] = bv;
          }
        }
      }
    }
  }
  if (STATS) {
    __syncthreads();                 // all ds_reads done; safe to reuse LDS
    float* ls = (float*)lds;         // ls[0:128]=sum, ls[128:256]=sumsq
    ls[tid] = 0.f;
    __syncthreads();
    #pragma unroll
    for (int n = 0; n < 4; ++n) {
      int col = wcb + n * 16 + lrow;
      atomicAdd(&ls[col], colS[n]);
      atomicAdd(&ls[128 + col], colS2[n]);
    }
    __syncthreads();
    if (tid < 128) {
      int gn = n0 + tid;
      if (gn < N) {
        atomicAdd(&bsum[gn], ls[tid]);
        atomicAdd(&bsumsq[gn], ls[128 + tid]);
      }
    }
  }
}

// ---------------- BN finalize / apply ----------------
__global__ void k_bn_finalize(const float* __restrict__ sum, const float* __restrict__ sumsq,
                              float* __restrict__ mu, float* __restrict__ rs, int C, float invN) {
  int c = blockIdx.x * 256 + threadIdx.x;
  if (c >= C) return;
  float m = sum[c] * invN;
  float var = fmaxf(sumsq[c] * invN - m * m, 0.f);
  mu[c] = m; rs[c] = rsqrtf(var + 1e-5f);
}

__global__ void k_bn_apply_relu(u16* __restrict__ h, const float* __restrict__ mu,
                                const float* __restrict__ rs, const float* __restrict__ g,
                                const float* __restrict__ b, long total4, int Ccols, int ld) {
  long i = (long)blockIdx.x * 256 + threadIdx.x;
  if (i >= total4) return;
  long e = i * 4;
  int c = (int)(e % Ccols);
  long r = e / Ccols;
  u16* p = h + (size_t)r * ld + c;
  ushort4 v = *(ushort4*)p;
  float f0 = b2f(v.x), f1 = b2f(v.y), f2 = b2f(v.z), f3 = b2f(v.w);
  f0 = g[c + 0] * (f0 - mu[c + 0]) * rs[c + 0] + b[c + 0];
  f1 = g[c + 1] * (f1 - mu[c + 1]) * rs[c + 1] + b[c + 1];
  f2 = g[c + 2] * (f2 - mu[c + 2]) * rs[c + 2] + b[c + 2];
  f3 = g[c + 3] * (f3 - mu[c + 3]) * rs[c + 3] + b[c + 3];
  v.x = f2b(f0 > 0.f ? f0 : 0.f);
  v.y = f2b(f1 > 0.f ? f1 : 0.f);
  v.z = f2b(f2 > 0.f ? f2 : 0.f);
  v.w = f2b(f3 > 0.f ? f3 : 0.f);
  *(ushort4*)p = v;
}

// ---------------- FC4 + log_softmax ----------------
__global__ void k_fc4_logsoftmax(const u16* __restrict__ h, const float* __restrict__ W,
                                 const float* __restrict__ b, float* __restrict__ out) {
  int n = blockIdx.x;
  int lane = threadIdx.x;  // 64
  const u16* row = h + (size_t)n * HH1;
  float hv[4];
  #pragma unroll
  for (int j = 0; j < 4; ++j) hv[j] = b2f(row[lane + j * 64]);
  float logits[OUTC];
  #pragma unroll
  for (int o = 0; o < OUTC; ++o) {
    float p = 0.f;
    #pragma unroll
    for (int j = 0; j < 4; ++j) p += hv[j] * W[(size_t)(lane + j * 64) * OUTC + o];
    #pragma unroll
    for (int off = 32; off > 0; off >>= 1) p += __shfl_down(p, off);
    logits[o] = p;
  }
  if (lane == 0) {
    float mx = -1e30f;
    #pragma unroll
    for (int o = 0; o < OUTC; ++o) { logits[o] += b[o]; mx = fmaxf(mx, logits[o]); }
    float se = 0.f;
    #pragma unroll
    for (int o = 0; o < OUTC; ++o) se += expf(logits[o] - mx);
    float ls = mx + logf(se);
    #pragma unroll
    for (int o = 0; o < OUTC; ++o) out[(size_t)n * OUTC + o] = logits[o] - ls;
  }
}

// ---------------- launch ----------------
extern "C" void kernel_launch(void* const* d_in, const int* in_sizes, int n_in,
                              void* d_out, int out_size, void* d_ws, size_t ws_size,
                              hipStream_t stream) {
  const float* x    = (const float*)d_in[0];
  const int*   ei   = (const int*)d_in[1];
  const float* g1Ws = (const float*)d_in[2];
  const float* g1Wd = (const float*)d_in[3];
  const float* g1as = (const float*)d_in[4];
  const float* g1ad = (const float*)d_in[5];
  const float* g1b  = (const float*)d_in[6];
  const float* g2Ws = (const float*)d_in[7];
  const float* g2Wd = (const float*)d_in[8];
  const float* g2as = (const float*)d_in[9];
  const float* g2ad = (const float*)d_in[10];
  const float* g2b  = (const float*)d_in[11];
  const float* f1W  = (const float*)d_in[12];
  const float* f1b  = (const float*)d_in[13];
  const float* bn1g = (const float*)d_in[14];
  const float* bn1b = (const float*)d_in[15];
  const float* f2W  = (const float*)d_in[16];
  const float* f2b_ = (const float*)d_in[17];
  const float* bn2g = (const float*)d_in[18];
  const float* bn2b = (const float*)d_in[19];
  const float* f3W  = (const float*)d_in[20];
  const float* f3b  = (const float*)d_in[21];
  const float* bn3g = (const float*)d_in[22];
  const float* bn3b = (const float*)d_in[23];
  const float* f4W  = (const float*)d_in[24];
  const float* f4b  = (const float*)d_in[25];
  float* out = (float*)d_out;
  (void)in_sizes; (void)n_in; (void)out_size; (void)ws_size;

  // ---- workspace layout (lifetime-overlapped; peak ~213.3 MB) ----
  char* Wb = (char*)d_ws;
  size_t off = 0;
  auto alloc = [&](size_t bytes) -> char* {
    char* p = Wb + off;
    off = (off + bytes + 255) & ~(size_t)255;
    return p;
  };
  u16* h3   = (u16*)Wb;                              // 20000*4096*2 = 163.84 MB
  u16* xs2  = (u16*)alloc((size_t)NN * HH2 * 2);
  u16* xs1  = (u16*)alloc((size_t)NN * HH1 * 2);
  u16* xb   = (u16*)alloc((size_t)NN * DD * 2);
  u16* h1   = (u16*)alloc((size_t)NN * HH1 * 2);
  u16* h5   = (u16*)alloc((size_t)NN * HH1 * 2);     // FC3 out (h3 dead by then)
  u16* Bt1  = (u16*)alloc((size_t)HH1 * DD * 2);
  u16* Bt2  = (u16*)alloc((size_t)HH2 * HH1 * 2);
  int* esrc   = (int*)alloc((size_t)EA * 4);
  int* rowptr = (int*)alloc((NN + 1) * 4);
  int* cursor = (int*)alloc(NN * 4);
  int* counts = (int*)alloc(NN * 4);
  float* als1 = (float*)alloc(NN * 4);
  float* ald1 = (float*)alloc(NN * 4);
  float* als2 = (float*)alloc(NN * 4);
  float* ald2 = (float*)alloc(NN * 4);
  float* ps1  = (float*)alloc(1024 * 4);
  float* pd1  = (float*)alloc(1024 * 4);
  float* ps2  = (float*)alloc(1024 * 4);
  float* pd2  = (float*)alloc(1024 * 4);
  int* eflag  = (int*)alloc(256);
  // interior arena usage ~85 MB < 163.84 MB  ✓

  off = ((size_t)NN * CC1P * 2 + 255) & ~(size_t)255;
  u16* h2 = (u16*)alloc((size_t)NN * HH2 * 2);       // agg2 -> FC1
  u16* h4 = h2;                                       // FC2 -> FC3 (time-disjoint)
  u16* Bf = (u16*)alloc((size_t)HH2 * CC1P * 2);     // JIT-shared weight slab
  float* bsum   = (float*)alloc((size_t)CC1 * 2 * 4);
  float* bsumsq = bsum + CC1;                         // FIXED offset CC1 — always
  float* bmu    = (float*)alloc((size_t)CC1 * 4);
  float* brs    = (float*)alloc((size_t)CC1 * 4);

  // x -> bf16
  k_f32_to_bf16<<<CEILDIV(NN * DD, 256), 256, 0, stream>>>(x, xb, NN * DD);

  // edge dtype detect + CSR (shared by both GAT layers)
  k_detect_e64<<<1, 256, 0, stream>>>(ei, eflag);
  k_zero32<<<CEILDIV(NN, 256), 256, 0, stream>>>((unsigned int*)counts, NN);
  k_edge_count<<<CEILDIV(EA, 256), 256, 0, stream>>>(ei, eflag, counts);
  k_scan<<<1, 1024, 0, stream>>>(counts, rowptr, cursor, NN);
  k_edge_fill<<<CEILDIV(EA, 256), 256, 0, stream>>>(ei, eflag, cursor, esrc);

  // ---- GAT layer 1 ----
  k_convT<<<dim3(CEILDIV(HH1, 32), CEILDIV(DD, 32)), 256, 0, stream>>>(g1Ws, Bt1, DD, HH1, DD);
  k_proj_vec<<<DD, 64, 0, stream>>>(g1Ws, g1as, g1Wd, g1ad, ps1, pd1, DD, HH1);
  k_attn_logits<<<NN, 64, 0, stream>>>(xb, ps1, pd1, als1, ald1, DD);
  k_mfma_gemm<false, false><<<CEILDIV(HH1, 128) * CEILDIV(NN, 128), 256, 0, stream>>>(
      xb, Bt1, nullptr, xs1, NN, HH1, DD, HH1, CEILDIV(HH1, 128), nullptr, nullptr);
  k_gat_aggregate<1><<<NN, 256, 0, stream>>>(rowptr, esrc, als1, ald1, xs1, g1b, h1, HH1);

  // ---- GAT layer 2 ----
  k_convT<<<dim3(CEILDIV(HH2, 32), CEILDIV(HH1, 32)), 256, 0, stream>>>(g2Ws, Bt2, HH1, HH2, HH1);
  k_proj_vec<<<HH1, 64, 0, stream>>>(g2Ws, g2as, g2Wd, g2ad, ps2, pd2, HH1, HH2);
  k_attn_logits<<<NN, 64, 0, stream>>>(h1, ps2, pd2, als2, ald2, HH1);
  k_mfma_gemm<false, false><<<CEILDIV(HH2, 128) * CEILDIV(NN, 128), 256, 0, stream>>>(
      h1, Bt2, nullptr, xs2, NN, HH2, HH1, HH2, CEILDIV(HH2, 128), nullptr, nullptr);
  k_gat_aggregate<4><<<NN, 256, 0, stream>>>(rowptr, esrc, als2, ald2, xs2, g2b, h2, HH2);

  // ---- FC1 + BN1 + ReLU ----  (stats fused into GEMM epilogue; full 2*CC1 clear)
  k_convT<<<dim3(CEILDIV(CC1, 32), CEILDIV(HH2, 32)), 256, 0, stream>>>(f1W, Bf, HH2, CC1, HH2);
  k_zero32<<<CEILDIV(2 * CC1, 256), 256, 0, stream>>>((unsigned int*)bsum, 2 * CC1);
  k_mfma_gemm<true, true><<<CEILDIV(CC1, 128) * CEILDIV(NN, 128), 256, 0, stream>>>(
      h2, Bf, f1b, h3, NN, CC1, HH2, CC1P, CEILDIV(CC1, 128), bsum, bsumsq);
  k_bn_finalize<<<CEILDIV(CC1, 256), 256, 0, stream>>>(bsum, bsumsq, bmu, brs, CC1, 1.f / NN);
  k_bn_apply_relu<<<CEILDIV((long)NN * CC1 / 4, 256), 256, 0, stream>>>(
      h3, bmu, brs, bn1g, bn1b, (long)NN * CC1 / 4, CC1, CC1P);

  // ---- FC2 + BN2 + ReLU ----  (K padded to 4096)
  k_convT<<<dim3(CEILDIV(HH2, 32), CEILDIV(CC1P, 32)), 256, 0, stream>>>(f2W, Bf, CC1, HH2, CC1P);
  k_zero32<<<CEILDIV(2 * CC1, 256), 256, 0, stream>>>((unsigned int*)bsum, 2 * CC1);
  k_mfma_gemm<true, true><<<CEILDIV(HH2, 128) * CEILDIV(NN, 128), 256, 0, stream>>>(
      h3, Bf, f2b_, h4, NN, HH2, CC1P, HH2, CEILDIV(HH2, 128), bsum, bsumsq);
  k_bn_finalize<<<CEILDIV(HH2, 256), 256, 0, stream>>>(bsum, bsumsq, bmu, brs, HH2, 1.f / NN);
  k_bn_apply_relu<<<CEILDIV((long)NN * HH2 / 4, 256), 256, 0, stream>>>(
      h4, bmu, brs, bn2g, bn2b, (long)NN * HH2 / 4, HH2, HH2);

  // ---- FC3 + BN3 + ReLU ----  (h5 in arena A; h3 dead)
  k_convT<<<dim3(CEILDIV(HH1, 32), CEILDIV(HH2, 32)), 256, 0, stream>>>(f3W, Bf, HH2, HH1, HH2);
  k_zero32<<<CEILDIV(2 * CC1, 256), 256, 0, stream>>>((unsigned int*)bsum, 2 * CC1);
  k_mfma_gemm<true, true><<<CEILDIV(HH1, 128) * CEILDIV(NN, 128), 256, 0, stream>>>(
      h4, Bf, f3b, h5, NN, HH1, HH2, HH1, CEILDIV(HH1, 128), bsum, bsumsq);
  k_bn_finalize<<<CEILDIV(HH1, 256), 256, 0, stream>>>(bsum, bsumsq, bmu, brs, HH1, 1.f / NN);
  k_bn_apply_relu<<<CEILDIV((long)NN * HH1 / 4, 256), 256, 0, stream>>>(
      h5, bmu, brs, bn3g, bn3b, (long)NN * HH1 / 4, HH1, HH1);

  // ---- FC4 + log_softmax ----
  k_fc4_logsoftmax<<<NN, 64, 0, stream>>>(h5, f4W, f4b, out);
}

// Round 14
// 1006.150 us; speedup vs baseline: 1.0514x; 1.0514x over previous
//
#include <hip/hip_runtime.h>

#define NN 20000
#define EE 320000
#define DD 256
#define HH1 256
#define HH2 1024
#define CC1 4092
#define CC1P 4096
#define OUTC 10
#define EA (EE + NN)

#define CEILDIV(a,b) (((a)+(b)-1)/(b))

typedef unsigned short u16;
typedef __attribute__((ext_vector_type(8))) short bf16x8;
typedef __attribute__((ext_vector_type(4))) float f32x4;

__device__ __forceinline__ float b2f(unsigned short u) {
  union { unsigned int i; float f; } v; v.i = ((unsigned int)u) << 16; return v.f;
}
__device__ __forceinline__ unsigned short f2b(float f) {
  unsigned int x = __float_as_uint(f);
  unsigned int r = (x + 0x7fffu + ((x >> 16) & 1u)) >> 16;
  return (unsigned short)r;
}

// global -> LDS direct (16B/lane). LDS dest = wave-uniform base + lane*16.
__device__ __forceinline__ void gload16(const u16* g, u16* l) {
  __builtin_amdgcn_global_load_lds(
      (const __attribute__((address_space(1))) unsigned int*)(unsigned long long)(const void*)g,
      (__attribute__((address_space(3))) unsigned int*)(unsigned int)(unsigned long long)(void*)l,
      16, 0, 0);
}

// ---------------- utility ----------------
__global__ void k_zero32(unsigned int* __restrict__ p, int n) {
  int i = blockIdx.x * 256 + threadIdx.x;
  if (i < n) p[i] = 0u;
}

__global__ void k_f32_to_bf16(const float* __restrict__ in, u16* __restrict__ out, int n) {
  int i = blockIdx.x * 256 + threadIdx.x;
  if (i < n) out[i] = f2b(in[i]);
}

// convert + transpose: W[K][N] f32 -> out[N][Kp] bf16, zero-filled for k in [K,Kp)
__global__ void k_convT(const float* __restrict__ in, u16* __restrict__ out,
                        int K, int N, int Kp) {
  __shared__ float tile[32][33];
  int kb = blockIdx.y * 32, nb = blockIdx.x * 32;
  int tx = threadIdx.x & 31, ty = threadIdx.x >> 5;  // ty 0..7
  #pragma unroll
  for (int i = 0; i < 32; i += 8) {
    int k = kb + ty + i, n = nb + tx;
    tile[ty + i][tx] = (k < K && n < N) ? in[(size_t)k * N + n] : 0.f;
  }
  __syncthreads();
  #pragma unroll
  for (int i = 0; i < 32; i += 8) {
    int n = nb + ty + i, k = kb + tx;
    if (n < N && k < Kp) out[(size_t)n * Kp + k] = f2b(tile[tx][ty + i]);
  }
}

// ---------------- edge dtype detection (int32 vs int64 storage) ----------------
__global__ void k_detect_e64(const int* __restrict__ ei, int* __restrict__ flag) {
  __shared__ int nz;
  if (threadIdx.x == 0) nz = 0;
  __syncthreads();
  if (ei[2 * threadIdx.x + 1] != 0) atomicOr(&nz, 1);
  __syncthreads();
  if (threadIdx.x == 0) *flag = (nz == 0) ? 1 : 0;
}

__device__ __forceinline__ int eread(const int* __restrict__ ei, int f64, int idx) {
  return f64 ? ei[(size_t)idx * 2] : ei[idx];
}

// ---------------- projected attention vectors: one wave per output row ----------------
__global__ void k_proj_vec(const float* __restrict__ Ws, const float* __restrict__ as_,
                           const float* __restrict__ Wd, const float* __restrict__ ad_,
                           float* __restrict__ ps, float* __restrict__ pd, int K, int F) {
  int k = blockIdx.x;
  if (k >= K) return;
  int lane = threadIdx.x;  // 64
  const float* wsr = Ws + (size_t)k * F;
  const float* wdr = Wd + (size_t)k * F;
  float s = 0.f, d = 0.f;
  for (int f = lane * 4; f < F; f += 256) {
    float4 w1 = *(const float4*)(wsr + f);
    float4 a1 = *(const float4*)(as_ + f);
    float4 w2 = *(const float4*)(wdr + f);
    float4 a2 = *(const float4*)(ad_ + f);
    s += w1.x * a1.x + w1.y * a1.y + w1.z * a1.z + w1.w * a1.w;
    d += w2.x * a2.x + w2.y * a2.y + w2.z * a2.z + w2.w * a2.w;
  }
  #pragma unroll
  for (int off = 32; off > 0; off >>= 1) {
    s += __shfl_xor(s, off);
    d += __shfl_xor(d, off);
  }
  if (lane == 0) { ps[k] = s; pd[k] = d; }
}

// ---------------- per-node attention logits ----------------
__global__ void k_attn_logits(const u16* __restrict__ act, const float* __restrict__ ps,
                              const float* __restrict__ pd, float* __restrict__ als,
                              float* __restrict__ ald, int K) {
  int n = blockIdx.x;
  int lane = threadIdx.x;
  const u16* row = act + (size_t)n * K;
  float s = 0.f, d = 0.f;
  for (int k = lane; k < K; k += 64) {
    float v = b2f(row[k]);
    s += v * ps[k]; d += v * pd[k];
  }
  #pragma unroll
  for (int off = 32; off > 0; off >>= 1) { s += __shfl_down(s, off); d += __shfl_down(d, off); }
  if (lane == 0) { als[n] = s; ald[n] = d; }
}

// ---------------- CSR build (round-3 exact: single-block scan) ----------------
__global__ void k_edge_count(const int* __restrict__ ei, const int* __restrict__ eflag,
                             int* __restrict__ counts) {
  int k = blockIdx.x * 256 + threadIdx.x;
  if (k >= EA) return;
  int f64 = *eflag;
  int dst = (k < EE) ? eread(ei, f64, EE + k) : (k - EE);
  if ((unsigned)dst < (unsigned)NN) atomicAdd(&counts[dst], 1);
}

__global__ void k_scan(const int* __restrict__ counts, int* __restrict__ rowptr,
                       int* __restrict__ cursor, int n) {
  __shared__ int sdata[1024];
  __shared__ int s_carry;
  if (threadIdx.x == 0) s_carry = 0;
  __syncthreads();
  for (int base = 0; base < n; base += 1024) {
    int idx = base + threadIdx.x;
    int v = (idx < n) ? counts[idx] : 0;
    sdata[threadIdx.x] = v;
    __syncthreads();
    for (int off = 1; off < 1024; off <<= 1) {
      int t = (threadIdx.x >= off) ? sdata[threadIdx.x - off] : 0;
      __syncthreads();
      sdata[threadIdx.x] += t;
      __syncthreads();
    }
    int incl = sdata[threadIdx.x];
    int carry = s_carry;
    if (idx < n) { int e = carry + incl - v; rowptr[idx] = e; cursor[idx] = e; }
    __syncthreads();
    if (threadIdx.x == 1023) s_carry = carry + sdata[1023];
    __syncthreads();
  }
  if (threadIdx.x == 0) rowptr[n] = s_carry;
}

__global__ void k_edge_fill(const int* __restrict__ ei, const int* __restrict__ eflag,
                            int* __restrict__ cursor, int* __restrict__ esrc) {
  int k = blockIdx.x * 256 + threadIdx.x;
  if (k >= EA) return;
  int f64 = *eflag;
  int src, dst;
  if (k < EE) { src = eread(ei, f64, k); dst = eread(ei, f64, EE + k); }
  else { src = dst = k - EE; }
  if ((unsigned)dst >= (unsigned)NN) return;
  if ((unsigned)src >= (unsigned)NN) src = 0;
  int pos = atomicAdd(&cursor[dst], 1);
  esrc[pos] = src;
}

// ---------------- GAT aggregation: wave-parallel softmax + chunked LDS alpha ----------
// Phase C gather now uses explicit 2-deep register prefetch: load(j+1) issues before
// the FMAs of j, hiding L2/L3 gather latency inside the runtime-count loop.
#define ACHUNK 512
template<int FPT>
__global__ __launch_bounds__(256) void k_gat_aggregate(
    const int* __restrict__ rowptr, const int* __restrict__ esrc,
    const float* __restrict__ als, const float* __restrict__ ald,
    const u16* __restrict__ xs, const float* __restrict__ bias,
    u16* __restrict__ h, int F) {
  __shared__ float red[256];
  __shared__ float salpha[ACHUNK];
  __shared__ int   ssrc[ACHUNK];
  int n = blockIdx.x;
  int tid = threadIdx.x;
  int beg = rowptr[n], end = rowptr[n + 1];
  float ad = ald[n];

  // phase A: block-parallel max
  float m = -1e30f;
  for (int j = beg + tid; j < end; j += 256) {
    float e = als[esrc[j]] + ad; e = (e < 0.f) ? 0.2f * e : e;
    m = fmaxf(m, e);
  }
  red[tid] = m; __syncthreads();
  #pragma unroll
  for (int s = 128; s > 0; s >>= 1) {
    if (tid < s) red[tid] = fmaxf(red[tid], red[tid + s]);
    __syncthreads();
  }
  m = red[0]; __syncthreads();

  // phase B: block-parallel sum of exp
  float ss = 0.f;
  for (int j = beg + tid; j < end; j += 256) {
    float e = als[esrc[j]] + ad; e = (e < 0.f) ? 0.2f * e : e;
    ss += expf(e - m);
  }
  red[tid] = ss; __syncthreads();
  #pragma unroll
  for (int s = 128; s > 0; s >>= 1) {
    if (tid < s) red[tid] += red[tid + s];
    __syncthreads();
  }
  float inv = 1.f / (red[0] + 1e-16f); __syncthreads();

  // phase C: chunked alpha into LDS, then gather-FMA with register prefetch
  float acc[FPT];
  #pragma unroll
  for (int i = 0; i < FPT; ++i) acc[i] = 0.f;
  int fbase = tid * FPT;
  for (int cbeg = beg; cbeg < end; cbeg += ACHUNK) {
    int cend = min(cbeg + ACHUNK, end);
    for (int j = cbeg + tid; j < cend; j += 256) {
      int s = esrc[j];
      float e = als[s] + ad; e = (e < 0.f) ? 0.2f * e : e;
      salpha[j - cbeg] = expf(e - m) * inv;
      ssrc[j - cbeg] = s;
    }
    __syncthreads();
    int cn = cend - cbeg;
    if (cn > 0) {
      if (FPT == 4) {
        float a0 = salpha[0];
        ushort4 v0 = *(const ushort4*)(xs + (size_t)ssrc[0] * F + fbase);
        for (int j = 1; j < cn; ++j) {
          float a1 = salpha[j];
          ushort4 v1 = *(const ushort4*)(xs + (size_t)ssrc[j] * F + fbase);
          acc[0] += a0 * b2f(v0.x);
          acc[1] += a0 * b2f(v0.y);
          acc[2] += a0 * b2f(v0.z);
          acc[3] += a0 * b2f(v0.w);
          a0 = a1; v0 = v1;
        }
        acc[0] += a0 * b2f(v0.x);
        acc[1] += a0 * b2f(v0.y);
        acc[2] += a0 * b2f(v0.z);
        acc[3] += a0 * b2f(v0.w);
      } else {
        float a0 = salpha[0];
        u16 v0 = xs[(size_t)ssrc[0] * F + fbase];
        for (int j = 1; j < cn; ++j) {
          float a1 = salpha[j];
          u16 v1 = xs[(size_t)ssrc[j] * F + fbase];
          acc[0] += a0 * b2f(v0);
          a0 = a1; v0 = v1;
        }
        acc[0] += a0 * b2f(v0);
      }
    }
    __syncthreads();
  }
  #pragma unroll
  for (int i = 0; i < FPT; ++i) {
    int f = fbase + i;
    float v = acc[i] + bias[f];
    h[(size_t)n * F + f] = f2b(v > 0.f ? v : 0.f);
  }
}

// ---------------- MFMA GEMM (round-10/12 exact, best measured): 128x128,
// 2-phase dbuf pipeline, vmcnt(0)+barrier per K-step, XCD band swizzle, fused
// bias + BN stats, regular (cached) C stores. ----
template<bool BIAS, bool STATS>
__global__ __launch_bounds__(256, 2) void k_mfma_gemm(
    const u16* __restrict__ A, const u16* __restrict__ Bt,
    const float* __restrict__ bias, u16* __restrict__ C,
    int M, int N, int K, int ldc, int nbx,
    float* __restrict__ bsum, float* __restrict__ bsumsq) {
  __shared__ u16 lds[16384];  // 2 buffers x (A 8KB + B 8KB) = 32 KB
  int tid = threadIdx.x;
  int lane = tid & 63;
  int w = tid >> 6;                 // wave 0..3; (w>>1, w&1) = 2x2 wave grid

  // bijective XCD band swizzle (m204)
  int nwg = gridDim.x;
  int id = blockIdx.x;
  int q = nwg >> 3, r = nwg & 7;
  int xcd = id & 7, pos = id >> 3;
  int swz = (xcd < r ? xcd * (q + 1) : r * (q + 1) + (xcd - r) * q) + pos;
  int m0 = (swz / nbx) * 128, n0 = (swz % nbx) * 128;

  int dr = lane >> 2;                          // dest row within 16-row chunk
  int ss = (lane & 3) ^ ((lane >> 3) & 3);     // inverse-swizzled source slot
  int lrow = lane & 15;                        // fragment row/col
  int lk = lane >> 4;                          // k-group 0..3

  f32x4 acc[4][4] = {};
  int c0 = w * 4;

  auto STAGE = [&](int k0, int bufb) {
    #pragma unroll
    for (int j = 0; j < 4; ++j) {
      int c = c0 + j;                 // chunk 0..15; 0..7 = A, 8..15 = B
      int tr = ((c & 7) << 4) + dr;   // tile row
      const u16* src;
      if (c < 8) {
        int rr = m0 + tr; rr = (rr < M) ? rr : (M - 1);
        src = A + (size_t)rr * K + k0 + ss * 8;
      } else {
        int rr = n0 + tr; rr = (rr < N) ? rr : (N - 1);
        src = Bt + (size_t)rr * K + k0 + ss * 8;
      }
      gload16(src, (u16*)((char*)lds + bufb + c * 1024));
    }
  };
  auto COMPUTE = [&](int bufb) {
    bf16x8 af[4], bfr[4];
    #pragma unroll
    for (int m = 0; m < 4; ++m) {
      int row = ((w >> 1) << 6) + m * 16 + lrow;
      af[m] = *(const bf16x8*)((const char*)lds + bufb + row * 64 +
                               ((lk ^ ((row >> 1) & 3)) << 4));
    }
    #pragma unroll
    for (int n = 0; n < 4; ++n) {
      int row = ((w & 1) << 6) + n * 16 + lrow;
      bfr[n] = *(const bf16x8*)((const char*)lds + bufb + 8192 + row * 64 +
                                ((lk ^ ((row >> 1) & 3)) << 4));
    }
    #pragma unroll
    for (int m = 0; m < 4; ++m)
      #pragma unroll
      for (int n = 0; n < 4; ++n)
        acc[m][n] = __builtin_amdgcn_mfma_f32_16x16x32_bf16(af[m], bfr[n], acc[m][n], 0, 0, 0);
  };

  int cur = 0;
  STAGE(0, 0);
  asm volatile("s_waitcnt vmcnt(0)" ::: "memory");
  __syncthreads();
  for (int k0 = 32; k0 < K; k0 += 32) {
    STAGE(k0, (cur ^ 1) * 16384);
    COMPUTE(cur * 16384);
    asm volatile("s_waitcnt vmcnt(0)" ::: "memory");
    __syncthreads();
    cur ^= 1;
  }
  COMPUTE(cur * 16384);

  // epilogue: C write (+bias) and optional fused column stats
  int wrb = (w >> 1) * 64, wcb = (w & 1) * 64;
  float colS[4] = {0.f, 0.f, 0.f, 0.f}, colS2[4] = {0.f, 0.f, 0.f, 0.f};
  #pragma unroll
  for (int m = 0; m < 4; ++m) {
    #pragma unroll
    for (int qq = 0; qq < 4; ++qq) {
      int gm = m0 + wrb + m * 16 + lk * 4 + qq;  // C/D: row=(lane>>4)*4+reg
      bool okm = gm < M;
      #pragma unroll
      for (int n = 0; n < 4; ++n) {
        int gn = n0 + wcb + n * 16 + lrow;       // C/D: col=lane&15
        if (gn >= N) continue;
        float v = acc[m][n][qq];
        if (BIAS) v += bias[gn];
        if (okm) {
          C[(size_t)gm * ldc + gn] = f2b(v);
          if (STATS) { colS[n] += v; colS2[n] += v * v; }
        }
      }
    }
  }
  if (STATS) {
    __syncthreads();                 // all ds_reads done; safe to reuse LDS
    float* ls = (float*)lds;         // ls[0:128]=sum, ls[128:256]=sumsq
    ls[tid] = 0.f;
    __syncthreads();
    #pragma unroll
    for (int n = 0; n < 4; ++n) {
      int col = wcb + n * 16 + lrow;
      atomicAdd(&ls[col], colS[n]);
      atomicAdd(&ls[128 + col], colS2[n]);
    }
    __syncthreads();
    if (tid < 128) {
      int gn = n0 + tid;
      if (gn < N) {
        atomicAdd(&bsum[gn], ls[tid]);
        atomicAdd(&bsumsq[gn], ls[128 + tid]);
      }
    }
  }
}

// ---------------- BN finalize / apply ----------------
__global__ void k_bn_finalize(const float* __restrict__ sum, const float* __restrict__ sumsq,
                              float* __restrict__ mu, float* __restrict__ rs, int C, float invN) {
  int c = blockIdx.x * 256 + threadIdx.x;
  if (c >= C) return;
  float m = sum[c] * invN;
  float var = fmaxf(sumsq[c] * invN - m * m, 0.f);
  mu[c] = m; rs[c] = rsqrtf(var + 1e-5f);
}

__global__ void k_bn_apply_relu(u16* __restrict__ h, const float* __restrict__ mu,
                                const float* __restrict__ rs, const float* __restrict__ g,
                                const float* __restrict__ b, long total4, int Ccols, int ld) {
  long i = (long)blockIdx.x * 256 + threadIdx.x;
  if (i >= total4) return;
  long e = i * 4;
  int c = (int)(e % Ccols);
  long r = e / Ccols;
  u16* p = h + (size_t)r * ld + c;
  ushort4 v = *(ushort4*)p;
  float f0 = b2f(v.x), f1 = b2f(v.y), f2 = b2f(v.z), f3 = b2f(v.w);
  f0 = g[c + 0] * (f0 - mu[c + 0]) * rs[c + 0] + b[c + 0];
  f1 = g[c + 1] * (f1 - mu[c + 1]) * rs[c + 1] + b[c + 1];
  f2 = g[c + 2] * (f2 - mu[c + 2]) * rs[c + 2] + b[c + 2];
  f3 = g[c + 3] * (f3 - mu[c + 3]) * rs[c + 3] + b[c + 3];
  v.x = f2b(f0 > 0.f ? f0 : 0.f);
  v.y = f2b(f1 > 0.f ? f1 : 0.f);
  v.z = f2b(f2 > 0.f ? f2 : 0.f);
  v.w = f2b(f3 > 0.f ? f3 : 0.f);
  *(ushort4*)p = v;
}

// ---------------- FC4 + log_softmax ----------------
__global__ void k_fc4_logsoftmax(const u16* __restrict__ h, const float* __restrict__ W,
                                 const float* __restrict__ b, float* __restrict__ out) {
  int n = blockIdx.x;
  int lane = threadIdx.x;  // 64
  const u16* row = h + (size_t)n * HH1;
  float hv[4];
  #pragma unroll
  for (int j = 0; j < 4; ++j) hv[j] = b2f(row[lane + j * 64]);
  float logits[OUTC];
  #pragma unroll
  for (int o = 0; o < OUTC; ++o) {
    float p = 0.f;
    #pragma unroll
    for (int j = 0; j < 4; ++j) p += hv[j] * W[(size_t)(lane + j * 64) * OUTC + o];
    #pragma unroll
    for (int off = 32; off > 0; off >>= 1) p += __shfl_down(p, off);
    logits[o] = p;
  }
  if (lane == 0) {
    float mx = -1e30f;
    #pragma unroll
    for (int o = 0; o < OUTC; ++o) { logits[o] += b[o]; mx = fmaxf(mx, logits[o]); }
    float se = 0.f;
    #pragma unroll
    for (int o = 0; o < OUTC; ++o) se += expf(logits[o] - mx);
    float ls = mx + logf(se);
    #pragma unroll
    for (int o = 0; o < OUTC; ++o) out[(size_t)n * OUTC + o] = logits[o] - ls;
  }
}

// ---------------- launch ----------------
extern "C" void kernel_launch(void* const* d_in, const int* in_sizes, int n_in,
                              void* d_out, int out_size, void* d_ws, size_t ws_size,
                              hipStream_t stream) {
  const float* x    = (const float*)d_in[0];
  const int*   ei   = (const int*)d_in[1];
  const float* g1Ws = (const float*)d_in[2];
  const float* g1Wd = (const float*)d_in[3];
  const float* g1as = (const float*)d_in[4];
  const float* g1ad = (const float*)d_in[5];
  const float* g1b  = (const float*)d_in[6];
  const float* g2Ws = (const float*)d_in[7];
  const float* g2Wd = (const float*)d_in[8];
  const float* g2as = (const float*)d_in[9];
  const float* g2ad = (const float*)d_in[10];
  const float* g2b  = (const float*)d_in[11];
  const float* f1W  = (const float*)d_in[12];
  const float* f1b  = (const float*)d_in[13];
  const float* bn1g = (const float*)d_in[14];
  const float* bn1b = (const float*)d_in[15];
  const float* f2W  = (const float*)d_in[16];
  const float* f2b_ = (const float*)d_in[17];
  const float* bn2g = (const float*)d_in[18];
  const float* bn2b = (const float*)d_in[19];
  const float* f3W  = (const float*)d_in[20];
  const float* f3b  = (const float*)d_in[21];
  const float* bn3g = (const float*)d_in[22];
  const float* bn3b = (const float*)d_in[23];
  const float* f4W  = (const float*)d_in[24];
  const float* f4b  = (const float*)d_in[25];
  float* out = (float*)d_out;
  (void)in_sizes; (void)n_in; (void)out_size; (void)ws_size;

  // ---- workspace layout (lifetime-overlapped; peak ~213.3 MB) ----
  char* Wb = (char*)d_ws;
  size_t off = 0;
  auto alloc = [&](size_t bytes) -> char* {
    char* p = Wb + off;
    off = (off + bytes + 255) & ~(size_t)255;
    return p;
  };
  u16* h3   = (u16*)Wb;                              // 20000*4096*2 = 163.84 MB
  u16* xs2  = (u16*)alloc((size_t)NN * HH2 * 2);
  u16* xs1  = (u16*)alloc((size_t)NN * HH1 * 2);
  u16* xb   = (u16*)alloc((size_t)NN * DD * 2);
  u16* h1   = (u16*)alloc((size_t)NN * HH1 * 2);
  u16* h5   = (u16*)alloc((size_t)NN * HH1 * 2);     // FC3 out (h3 dead by then)
  u16* Bt1  = (u16*)alloc((size_t)HH1 * DD * 2);
  u16* Bt2  = (u16*)alloc((size_t)HH2 * HH1 * 2);
  int* esrc   = (int*)alloc((size_t)EA * 4);
  int* rowptr = (int*)alloc((NN + 1) * 4);
  int* cursor = (int*)alloc(NN * 4);
  int* counts = (int*)alloc(NN * 4);
  float* als1 = (float*)alloc(NN * 4);
  float* ald1 = (float*)alloc(NN * 4);
  float* als2 = (float*)alloc(NN * 4);
  float* ald2 = (float*)alloc(NN * 4);
  float* ps1  = (float*)alloc(1024 * 4);
  float* pd1  = (float*)alloc(1024 * 4);
  float* ps2  = (float*)alloc(1024 * 4);
  float* pd2  = (float*)alloc(1024 * 4);
  int* eflag  = (int*)alloc(256);
  // interior arena usage ~85 MB < 163.84 MB  ✓

  off = ((size_t)NN * CC1P * 2 + 255) & ~(size_t)255;
  u16* h2 = (u16*)alloc((size_t)NN * HH2 * 2);       // agg2 -> FC1
  u16* h4 = h2;                                       // FC2 -> FC3 (time-disjoint)
  u16* Bf = (u16*)alloc((size_t)HH2 * CC1P * 2);     // JIT-shared weight slab
  float* bsum   = (float*)alloc((size_t)CC1 * 2 * 4);
  float* bsumsq = bsum + CC1;                         // FIXED offset CC1 — always
  float* bmu    = (float*)alloc((size_t)CC1 * 4);
  float* brs    = (float*)alloc((size_t)CC1 * 4);

  // x -> bf16
  k_f32_to_bf16<<<CEILDIV(NN * DD, 256), 256, 0, stream>>>(x, xb, NN * DD);

  // edge dtype detect + CSR (shared by both GAT layers)
  k_detect_e64<<<1, 256, 0, stream>>>(ei, eflag);
  k_zero32<<<CEILDIV(NN, 256), 256, 0, stream>>>((unsigned int*)counts, NN);
  k_edge_count<<<CEILDIV(EA, 256), 256, 0, stream>>>(ei, eflag, counts);
  k_scan<<<1, 1024, 0, stream>>>(counts, rowptr, cursor, NN);
  k_edge_fill<<<CEILDIV(EA, 256), 256, 0, stream>>>(ei, eflag, cursor, esrc);

  // ---- GAT layer 1 ----
  k_convT<<<dim3(CEILDIV(HH1, 32), CEILDIV(DD, 32)), 256, 0, stream>>>(g1Ws, Bt1, DD, HH1, DD);
  k_proj_vec<<<DD, 64, 0, stream>>>(g1Ws, g1as, g1Wd, g1ad, ps1, pd1, DD, HH1);
  k_attn_logits<<<NN, 64, 0, stream>>>(xb, ps1, pd1, als1, ald1, DD);
  k_mfma_gemm<false, false><<<CEILDIV(HH1, 128) * CEILDIV(NN, 128), 256, 0, stream>>>(
      xb, Bt1, nullptr, xs1, NN, HH1, DD, HH1, CEILDIV(HH1, 128), nullptr, nullptr);
  k_gat_aggregate<1><<<NN, 256, 0, stream>>>(rowptr, esrc, als1, ald1, xs1, g1b, h1, HH1);

  // ---- GAT layer 2 ----
  k_convT<<<dim3(CEILDIV(HH2, 32), CEILDIV(HH1, 32)), 256, 0, stream>>>(g2Ws, Bt2, HH1, HH2, HH1);
  k_proj_vec<<<HH1, 64, 0, stream>>>(g2Ws, g2as, g2Wd, g2ad, ps2, pd2, HH1, HH2);
  k_attn_logits<<<NN, 64, 0, stream>>>(h1, ps2, pd2, als2, ald2, HH1);
  k_mfma_gemm<false, false><<<CEILDIV(HH2, 128) * CEILDIV(NN, 128), 256, 0, stream>>>(
      h1, Bt2, nullptr, xs2, NN, HH2, HH1, HH2, CEILDIV(HH2, 128), nullptr, nullptr);
  k_gat_aggregate<4><<<NN, 256, 0, stream>>>(rowptr, esrc, als2, ald2, xs2, g2b, h2, HH2);

  // ---- FC1 + BN1 + ReLU ----  (stats fused into GEMM epilogue; full 2*CC1 clear)
  k_convT<<<dim3(CEILDIV(CC1, 32), CEILDIV(HH2, 32)), 256, 0, stream>>>(f1W, Bf, HH2, CC1, HH2);
  k_zero32<<<CEILDIV(2 * CC1, 256), 256, 0, stream>>>((unsigned int*)bsum, 2 * CC1);
  k_mfma_gemm<true, true><<<CEILDIV(CC1, 128) * CEILDIV(NN, 128), 256, 0, stream>>>(
      h2, Bf, f1b, h3, NN, CC1, HH2, CC1P, CEILDIV(CC1, 128), bsum, bsumsq);
  k_bn_finalize<<<CEILDIV(CC1, 256), 256, 0, stream>>>(bsum, bsumsq, bmu, brs, CC1, 1.f / NN);
  k_bn_apply_relu<<<CEILDIV((long)NN * CC1 / 4, 256), 256, 0, stream>>>(
      h3, bmu, brs, bn1g, bn1b, (long)NN * CC1 / 4, CC1, CC1P);

  // ---- FC2 + BN2 + ReLU ----  (K padded to 4096)
  k_convT<<<dim3(CEILDIV(HH2, 32), CEILDIV(CC1P, 32)), 256, 0, stream>>>(f2W, Bf, CC1, HH2, CC1P);
  k_zero32<<<CEILDIV(2 * CC1, 256), 256, 0, stream>>>((unsigned int*)bsum, 2 * CC1);
  k_mfma_gemm<true, true><<<CEILDIV(HH2, 128) * CEILDIV(NN, 128), 256, 0, stream>>>(
      h3, Bf, f2b_, h4, NN, HH2, CC1P, HH2, CEILDIV(HH2, 128), bsum, bsumsq);
  k_bn_finalize<<<CEILDIV(HH2, 256), 256, 0, stream>>>(bsum, bsumsq, bmu, brs, HH2, 1.f / NN);
  k_bn_apply_relu<<<CEILDIV((long)NN * HH2 / 4, 256), 256, 0, stream>>>(
      h4, bmu, brs, bn2g, bn2b, (long)NN * HH2 / 4, HH2, HH2);

  // ---- FC3 + BN3 + ReLU ----  (h5 in arena A; h3 dead)
  k_convT<<<dim3(CEILDIV(HH1, 32), CEILDIV(HH2, 32)), 256, 0, stream>>>(f3W, Bf, HH2, HH1, HH2);
  k_zero32<<<CEILDIV(2 * CC1, 256), 256, 0, stream>>>((unsigned int*)bsum, 2 * CC1);
  k_mfma_gemm<true, true><<<CEILDIV(HH1, 128) * CEILDIV(NN, 128), 256, 0, stream>>>(
      h4, Bf, f3b, h5, NN, HH1, HH2, HH1, CEILDIV(HH1, 128), bsum, bsumsq);
  k_bn_finalize<<<CEILDIV(HH1, 256), 256, 0, stream>>>(bsum, bsumsq, bmu, brs, HH1, 1.f / NN);
  k_bn_apply_relu<<<CEILDIV((long)NN * HH1 / 4, 256), 256, 0, stream>>>(
      h5, bmu, brs, bn3g, bn3b, (long)NN * HH1 / 4, HH1, HH1);

  // ---- FC4 + log_softmax ----
  k_fc4_logsoftmax<<<NN, 64, 0, stream>>>(h5, f4W, f4b, out);
}

// Round 15
// 925.628 us; speedup vs baseline: 1.1428x; 1.0870x over previous
//
#include <hip/hip_runtime.h>

#define NN 20000
#define EE 320000
#define DD 256
#define HH1 256
#define HH2 1024
#define CC1 4092
#define CC1P 4096
#define OUTC 10
#define EA (EE + NN)

#define CEILDIV(a,b) (((a)+(b)-1)/(b))

typedef unsigned short u16;
typedef __attribute__((ext_vector_type(8))) short bf16x8;
typedef __attribute__((ext_vector_type(4))) float f32x4;

__device__ __forceinline__ float b2f(unsigned short u) {
  union { unsigned int i; float f; } v; v.i = ((unsigned int)u) << 16; return v.f;
}
__device__ __forceinline__ unsigned short f2b(float f) {
  unsigned int x = __float_as_uint(f);
  unsigned int r = (x + 0x7fffu + ((x >> 16) & 1u)) >> 16;
  return (unsigned short)r;
}

// global -> LDS direct (16B/lane). LDS dest = wave-uniform base + lane*16.
__device__ __forceinline__ void gload16(const u16* g, u16* l) {
  __builtin_amdgcn_global_load_lds(
      (const __attribute__((address_space(1))) unsigned int*)(unsigned long long)(const void*)g,
      (__attribute__((address_space(3))) unsigned int*)(unsigned int)(unsigned long long)(void*)l,
      16, 0, 0);
}

// ---------------- utility ----------------
__global__ void k_zero32(unsigned int* __restrict__ p, int n) {
  int i = blockIdx.x * 256 + threadIdx.x;
  if (i < n) p[i] = 0u;
}

__global__ void k_f32_to_bf16(const float* __restrict__ in, u16* __restrict__ out, int n) {
  int i = blockIdx.x * 256 + threadIdx.x;
  if (i < n) out[i] = f2b(in[i]);
}

// convert + transpose: W[K][N] f32 -> out[N][Kp] bf16, zero-filled for k in [K,Kp)
__global__ void k_convT(const float* __restrict__ in, u16* __restrict__ out,
                        int K, int N, int Kp) {
  __shared__ float tile[32][33];
  int kb = blockIdx.y * 32, nb = blockIdx.x * 32;
  int tx = threadIdx.x & 31, ty = threadIdx.x >> 5;  // ty 0..7
  #pragma unroll
  for (int i = 0; i < 32; i += 8) {
    int k = kb + ty + i, n = nb + tx;
    tile[ty + i][tx] = (k < K && n < N) ? in[(size_t)k * N + n] : 0.f;
  }
  __syncthreads();
  #pragma unroll
  for (int i = 0; i < 32; i += 8) {
    int n = nb + ty + i, k = kb + tx;
    if (n < N && k < Kp) out[(size_t)n * Kp + k] = f2b(tile[tx][ty + i]);
  }
}

// ---------------- edge dtype detection (int32 vs int64 storage) ----------------
__global__ void k_detect_e64(const int* __restrict__ ei, int* __restrict__ flag) {
  __shared__ int nz;
  if (threadIdx.x == 0) nz = 0;
  __syncthreads();
  if (ei[2 * threadIdx.x + 1] != 0) atomicOr(&nz, 1);
  __syncthreads();
  if (threadIdx.x == 0) *flag = (nz == 0) ? 1 : 0;
}

__device__ __forceinline__ int eread(const int* __restrict__ ei, int f64, int idx) {
  return f64 ? ei[(size_t)idx * 2] : ei[idx];
}

// ---------------- projected attention vectors: one wave per output row ----------------
__global__ void k_proj_vec(const float* __restrict__ Ws, const float* __restrict__ as_,
                           const float* __restrict__ Wd, const float* __restrict__ ad_,
                           float* __restrict__ ps, float* __restrict__ pd, int K, int F) {
  int k = blockIdx.x;
  if (k >= K) return;
  int lane = threadIdx.x;  // 64
  const float* wsr = Ws + (size_t)k * F;
  const float* wdr = Wd + (size_t)k * F;
  float s = 0.f, d = 0.f;
  for (int f = lane * 4; f < F; f += 256) {
    float4 w1 = *(const float4*)(wsr + f);
    float4 a1 = *(const float4*)(as_ + f);
    float4 w2 = *(const float4*)(wdr + f);
    float4 a2 = *(const float4*)(ad_ + f);
    s += w1.x * a1.x + w1.y * a1.y + w1.z * a1.z + w1.w * a1.w;
    d += w2.x * a2.x + w2.y * a2.y + w2.z * a2.z + w2.w * a2.w;
  }
  #pragma unroll
  for (int off = 32; off > 0; off >>= 1) {
    s += __shfl_xor(s, off);
    d += __shfl_xor(d, off);
  }
  if (lane == 0) { ps[k] = s; pd[k] = d; }
}

// ---------------- per-node attention logits ----------------
__global__ void k_attn_logits(const u16* __restrict__ act, const float* __restrict__ ps,
                              const float* __restrict__ pd, float* __restrict__ als,
                              float* __restrict__ ald, int K) {
  int n = blockIdx.x;
  int lane = threadIdx.x;
  const u16* row = act + (size_t)n * K;
  float s = 0.f, d = 0.f;
  for (int k = lane; k < K; k += 64) {
    float v = b2f(row[k]);
    s += v * ps[k]; d += v * pd[k];
  }
  #pragma unroll
  for (int off = 32; off > 0; off >>= 1) { s += __shfl_down(s, off); d += __shfl_down(d, off); }
  if (lane == 0) { als[n] = s; ald[n] = d; }
}

// ---------------- CSR build (round-3 exact: single-block scan) ----------------
__global__ void k_edge_count(const int* __restrict__ ei, const int* __restrict__ eflag,
                             int* __restrict__ counts) {
  int k = blockIdx.x * 256 + threadIdx.x;
  if (k >= EA) return;
  int f64 = *eflag;
  int dst = (k < EE) ? eread(ei, f64, EE + k) : (k - EE);
  if ((unsigned)dst < (unsigned)NN) atomicAdd(&counts[dst], 1);
}

__global__ void k_scan(const int* __restrict__ counts, int* __restrict__ rowptr,
                       int* __restrict__ cursor, int n) {
  __shared__ int sdata[1024];
  __shared__ int s_carry;
  if (threadIdx.x == 0) s_carry = 0;
  __syncthreads();
  for (int base = 0; base < n; base += 1024) {
    int idx = base + threadIdx.x;
    int v = (idx < n) ? counts[idx] : 0;
    sdata[threadIdx.x] = v;
    __syncthreads();
    for (int off = 1; off < 1024; off <<= 1) {
      int t = (threadIdx.x >= off) ? sdata[threadIdx.x - off] : 0;
      __syncthreads();
      sdata[threadIdx.x] += t;
      __syncthreads();
    }
    int incl = sdata[threadIdx.x];
    int carry = s_carry;
    if (idx < n) { int e = carry + incl - v; rowptr[idx] = e; cursor[idx] = e; }
    __syncthreads();
    if (threadIdx.x == 1023) s_carry = carry + sdata[1023];
    __syncthreads();
  }
  if (threadIdx.x == 0) rowptr[n] = s_carry;
}

__global__ void k_edge_fill(const int* __restrict__ ei, const int* __restrict__ eflag,
                            int* __restrict__ cursor, int* __restrict__ esrc) {
  int k = blockIdx.x * 256 + threadIdx.x;
  if (k >= EA) return;
  int f64 = *eflag;
  int src, dst;
  if (k < EE) { src = eread(ei, f64, k); dst = eread(ei, f64, EE + k); }
  else { src = dst = k - EE; }
  if ((unsigned)dst >= (unsigned)NN) return;
  if ((unsigned)src >= (unsigned)NN) src = 0;
  int pos = atomicAdd(&cursor[dst], 1);
  esrc[pos] = src;
}

// ---------------- GAT aggregation (round-12 exact: simple gather loop) ----------------
#define ACHUNK 512
template<int FPT>
__global__ __launch_bounds__(256) void k_gat_aggregate(
    const int* __restrict__ rowptr, const int* __restrict__ esrc,
    const float* __restrict__ als, const float* __restrict__ ald,
    const u16* __restrict__ xs, const float* __restrict__ bias,
    u16* __restrict__ h, int F) {
  __shared__ float red[256];
  __shared__ float salpha[ACHUNK];
  __shared__ int   ssrc[ACHUNK];
  int n = blockIdx.x;
  int tid = threadIdx.x;
  int beg = rowptr[n], end = rowptr[n + 1];
  float ad = ald[n];

  // phase A: block-parallel max
  float m = -1e30f;
  for (int j = beg + tid; j < end; j += 256) {
    float e = als[esrc[j]] + ad; e = (e < 0.f) ? 0.2f * e : e;
    m = fmaxf(m, e);
  }
  red[tid] = m; __syncthreads();
  #pragma unroll
  for (int s = 128; s > 0; s >>= 1) {
    if (tid < s) red[tid] = fmaxf(red[tid], red[tid + s]);
    __syncthreads();
  }
  m = red[0]; __syncthreads();

  // phase B: block-parallel sum of exp
  float ss = 0.f;
  for (int j = beg + tid; j < end; j += 256) {
    float e = als[esrc[j]] + ad; e = (e < 0.f) ? 0.2f * e : e;
    ss += expf(e - m);
  }
  red[tid] = ss; __syncthreads();
  #pragma unroll
  for (int s = 128; s > 0; s >>= 1) {
    if (tid < s) red[tid] += red[tid + s];
    __syncthreads();
  }
  float inv = 1.f / (red[0] + 1e-16f); __syncthreads();

  // phase C: chunked alpha into LDS, then gather-FMA
  float acc[FPT];
  #pragma unroll
  for (int i = 0; i < FPT; ++i) acc[i] = 0.f;
  int fbase = tid * FPT;
  for (int cbeg = beg; cbeg < end; cbeg += ACHUNK) {
    int cend = min(cbeg + ACHUNK, end);
    for (int j = cbeg + tid; j < cend; j += 256) {
      int s = esrc[j];
      float e = als[s] + ad; e = (e < 0.f) ? 0.2f * e : e;
      salpha[j - cbeg] = expf(e - m) * inv;
      ssrc[j - cbeg] = s;
    }
    __syncthreads();
    int cn = cend - cbeg;
    for (int j = 0; j < cn; ++j) {
      float a = salpha[j];
      const u16* rowp = xs + (size_t)ssrc[j] * F + fbase;
      if (FPT == 4) {
        ushort4 v4 = *(const ushort4*)rowp;
        acc[0] += a * b2f(v4.x);
        acc[1] += a * b2f(v4.y);
        acc[2] += a * b2f(v4.z);
        acc[3] += a * b2f(v4.w);
      } else {
        acc[0] += a * b2f(rowp[0]);
      }
    }
    __syncthreads();
  }
  #pragma unroll
  for (int i = 0; i < FPT; ++i) {
    int f = fbase + i;
    float v = acc[i] + bias[f];
    h[(size_t)n * F + f] = f2b(v > 0.f ? v : 0.f);
  }
}

// ---------------- MFMA GEMM: 128x128, 2-phase dbuf pipeline, XCD band swizzle ----
// Stats epilogue now barrier-free: shfl_xor(16/32) reduces colS over the 4 lk lanes
// per column, then lk==0 lanes issue 2 global atomics/col (no LDS phase, no syncs).
template<bool BIAS, bool STATS>
__global__ __launch_bounds__(256, 2) void k_mfma_gemm(
    const u16* __restrict__ A, const u16* __restrict__ Bt,
    const float* __restrict__ bias, u16* __restrict__ C,
    int M, int N, int K, int ldc, int nbx,
    float* __restrict__ bsum, float* __restrict__ bsumsq) {
  __shared__ u16 lds[16384];  // 2 buffers x (A 8KB + B 8KB) = 32 KB
  int tid = threadIdx.x;
  int lane = tid & 63;
  int w = tid >> 6;                 // wave 0..3; (w>>1, w&1) = 2x2 wave grid

  // bijective XCD band swizzle (m204)
  int nwg = gridDim.x;
  int id = blockIdx.x;
  int q = nwg >> 3, r = nwg & 7;
  int xcd = id & 7, pos = id >> 3;
  int swz = (xcd < r ? xcd * (q + 1) : r * (q + 1) + (xcd - r) * q) + pos;
  int m0 = (swz / nbx) * 128, n0 = (swz % nbx) * 128;

  int dr = lane >> 2;                          // dest row within 16-row chunk
  int ss = (lane & 3) ^ ((lane >> 3) & 3);     // inverse-swizzled source slot
  int lrow = lane & 15;                        // fragment row/col
  int lk = lane >> 4;                          // k-group 0..3

  f32x4 acc[4][4] = {};
  int c0 = w * 4;

  auto STAGE = [&](int k0, int bufb) {
    #pragma unroll
    for (int j = 0; j < 4; ++j) {
      int c = c0 + j;                 // chunk 0..15; 0..7 = A, 8..15 = B
      int tr = ((c & 7) << 4) + dr;   // tile row
      const u16* src;
      if (c < 8) {
        int rr = m0 + tr; rr = (rr < M) ? rr : (M - 1);
        src = A + (size_t)rr * K + k0 + ss * 8;
      } else {
        int rr = n0 + tr; rr = (rr < N) ? rr : (N - 1);
        src = Bt + (size_t)rr * K + k0 + ss * 8;
      }
      gload16(src, (u16*)((char*)lds + bufb + c * 1024));
    }
  };
  auto COMPUTE = [&](int bufb) {
    bf16x8 af[4], bfr[4];
    #pragma unroll
    for (int m = 0; m < 4; ++m) {
      int row = ((w >> 1) << 6) + m * 16 + lrow;
      af[m] = *(const bf16x8*)((const char*)lds + bufb + row * 64 +
                               ((lk ^ ((row >> 1) & 3)) << 4));
    }
    #pragma unroll
    for (int n = 0; n < 4; ++n) {
      int row = ((w & 1) << 6) + n * 16 + lrow;
      bfr[n] = *(const bf16x8*)((const char*)lds + bufb + 8192 + row * 64 +
                                ((lk ^ ((row >> 1) & 3)) << 4));
    }
    #pragma unroll
    for (int m = 0; m < 4; ++m)
      #pragma unroll
      for (int n = 0; n < 4; ++n)
        acc[m][n] = __builtin_amdgcn_mfma_f32_16x16x32_bf16(af[m], bfr[n], acc[m][n], 0, 0, 0);
  };

  int cur = 0;
  STAGE(0, 0);
  asm volatile("s_waitcnt vmcnt(0)" ::: "memory");
  __syncthreads();
  for (int k0 = 32; k0 < K; k0 += 32) {
    STAGE(k0, (cur ^ 1) * 16384);
    COMPUTE(cur * 16384);
    asm volatile("s_waitcnt vmcnt(0)" ::: "memory");
    __syncthreads();
    cur ^= 1;
  }
  COMPUTE(cur * 16384);

  // epilogue: C write (+bias) and optional fused column stats
  int wrb = (w >> 1) * 64, wcb = (w & 1) * 64;
  float colS[4] = {0.f, 0.f, 0.f, 0.f}, colS2[4] = {0.f, 0.f, 0.f, 0.f};
  #pragma unroll
  for (int m = 0; m < 4; ++m) {
    #pragma unroll
    for (int qq = 0; qq < 4; ++qq) {
      int gm = m0 + wrb + m * 16 + lk * 4 + qq;  // C/D: row=(lane>>4)*4+reg
      bool okm = gm < M;
      #pragma unroll
      for (int n = 0; n < 4; ++n) {
        int gn = n0 + wcb + n * 16 + lrow;       // C/D: col=lane&15
        if (gn >= N) continue;
        float v = acc[m][n][qq];
        if (BIAS) v += bias[gn];
        if (okm) {
          C[(size_t)gm * ldc + gn] = f2b(v);
          if (STATS) { colS[n] += v; colS2[n] += v * v; }
        }
      }
    }
  }
  if (STATS) {
    // cross-lane reduce over lk (lanes with same lrow, stride 16), no barriers/LDS
    #pragma unroll
    for (int n = 0; n < 4; ++n) {
      colS[n]  += __shfl_xor(colS[n], 16);
      colS[n]  += __shfl_xor(colS[n], 32);
      colS2[n] += __shfl_xor(colS2[n], 16);
      colS2[n] += __shfl_xor(colS2[n], 32);
    }
    if (lk == 0) {
      #pragma unroll
      for (int n = 0; n < 4; ++n) {
        int gn = n0 + wcb + n * 16 + lrow;
        if (gn < N) {
          atomicAdd(&bsum[gn], colS[n]);
          atomicAdd(&bsumsq[gn], colS2[n]);
        }
      }
    }
  }
}

// ---------------- BN finalize / apply ----------------
__global__ void k_bn_finalize(const float* __restrict__ sum, const float* __restrict__ sumsq,
                              float* __restrict__ mu, float* __restrict__ rs, int C, float invN) {
  int c = blockIdx.x * 256 + threadIdx.x;
  if (c >= C) return;
  float m = sum[c] * invN;
  float var = fmaxf(sumsq[c] * invN - m * m, 0.f);
  mu[c] = m; rs[c] = rsqrtf(var + 1e-5f);
}

__global__ void k_bn_apply_relu(u16* __restrict__ h, const float* __restrict__ mu,
                                const float* __restrict__ rs, const float* __restrict__ g,
                                const float* __restrict__ b, long total4, int Ccols, int ld) {
  long i = (long)blockIdx.x * 256 + threadIdx.x;
  if (i >= total4) return;
  long e = i * 4;
  int c = (int)(e % Ccols);
  long r = e / Ccols;
  u16* p = h + (size_t)r * ld + c;
  ushort4 v = *(ushort4*)p;
  float f0 = b2f(v.x), f1 = b2f(v.y), f2 = b2f(v.z), f3 = b2f(v.w);
  f0 = g[c + 0] * (f0 - mu[c + 0]) * rs[c + 0] + b[c + 0];
  f1 = g[c + 1] * (f1 - mu[c + 1]) * rs[c + 1] + b[c + 1];
  f2 = g[c + 2] * (f2 - mu[c + 2]) * rs[c + 2] + b[c + 2];
  f3 = g[c + 3] * (f3 - mu[c + 3]) * rs[c + 3] + b[c + 3];
  v.x = f2b(f0 > 0.f ? f0 : 0.f);
  v.y = f2b(f1 > 0.f ? f1 : 0.f);
  v.z = f2b(f2 > 0.f ? f2 : 0.f);
  v.w = f2b(f3 > 0.f ? f3 : 0.f);
  *(ushort4*)p = v;
}

// ---------------- FC4 + log_softmax ----------------
__global__ void k_fc4_logsoftmax(const u16* __restrict__ h, const float* __restrict__ W,
                                 const float* __restrict__ b, float* __restrict__ out) {
  int n = blockIdx.x;
  int lane = threadIdx.x;  // 64
  const u16* row = h + (size_t)n * HH1;
  float hv[4];
  #pragma unroll
  for (int j = 0; j < 4; ++j) hv[j] = b2f(row[lane + j * 64]);
  float logits[OUTC];
  #pragma unroll
  for (int o = 0; o < OUTC; ++o) {
    float p = 0.f;
    #pragma unroll
    for (int j = 0; j < 4; ++j) p += hv[j] * W[(size_t)(lane + j * 64) * OUTC + o];
    #pragma unroll
    for (int off = 32; off > 0; off >>= 1) p += __shfl_down(p, off);
    logits[o] = p;
  }
  if (lane == 0) {
    float mx = -1e30f;
    #pragma unroll
    for (int o = 0; o < OUTC; ++o) { logits[o] += b[o]; mx = fmaxf(mx, logits[o]); }
    float se = 0.f;
    #pragma unroll
    for (int o = 0; o < OUTC; ++o) se += expf(logits[o] - mx);
    float ls = mx + logf(se);
    #pragma unroll
    for (int o = 0; o < OUTC; ++o) out[(size_t)n * OUTC + o] = logits[o] - ls;
  }
}

// ---------------- launch ----------------
extern "C" void kernel_launch(void* const* d_in, const int* in_sizes, int n_in,
                              void* d_out, int out_size, void* d_ws, size_t ws_size,
                              hipStream_t stream) {
  const float* x    = (const float*)d_in[0];
  const int*   ei   = (const int*)d_in[1];
  const float* g1Ws = (const float*)d_in[2];
  const float* g1Wd = (const float*)d_in[3];
  const float* g1as = (const float*)d_in[4];
  const float* g1ad = (const float*)d_in[5];
  const float* g1b  = (const float*)d_in[6];
  const float* g2Ws = (const float*)d_in[7];
  const float* g2Wd = (const float*)d_in[8];
  const float* g2as = (const float*)d_in[9];
  const float* g2ad = (const float*)d_in[10];
  const float* g2b  = (const float*)d_in[11];
  const float* f1W  = (const float*)d_in[12];
  const float* f1b  = (const float*)d_in[13];
  const float* bn1g = (const float*)d_in[14];
  const float* bn1b = (const float*)d_in[15];
  const float* f2W  = (const float*)d_in[16];
  const float* f2b_ = (const float*)d_in[17];
  const float* bn2g = (const float*)d_in[18];
  const float* bn2b = (const float*)d_in[19];
  const float* f3W  = (const float*)d_in[20];
  const float* f3b  = (const float*)d_in[21];
  const float* bn3g = (const float*)d_in[22];
  const float* bn3b = (const float*)d_in[23];
  const float* f4W  = (const float*)d_in[24];
  const float* f4b  = (const float*)d_in[25];
  float* out = (float*)d_out;
  (void)in_sizes; (void)n_in; (void)out_size; (void)ws_size;

  // ---- workspace layout (lifetime-overlapped; peak ~213.3 MB) ----
  char* Wb = (char*)d_ws;
  size_t off = 0;
  auto alloc = [&](size_t bytes) -> char* {
    char* p = Wb + off;
    off = (off + bytes + 255) & ~(size_t)255;
    return p;
  };
  u16* h3   = (u16*)Wb;                              // 20000*4096*2 = 163.84 MB
  u16* xs2  = (u16*)alloc((size_t)NN * HH2 * 2);
  u16* xs1  = (u16*)alloc((size_t)NN * HH1 * 2);
  u16* xb   = (u16*)alloc((size_t)NN * DD * 2);
  u16* h1   = (u16*)alloc((size_t)NN * HH1 * 2);
  u16* h5   = (u16*)alloc((size_t)NN * HH1 * 2);     // FC3 out (h3 dead by then)
  u16* Bt1  = (u16*)alloc((size_t)HH1 * DD * 2);
  u16* Bt2  = (u16*)alloc((size_t)HH2 * HH1 * 2);
  int* esrc   = (int*)alloc((size_t)EA * 4);
  int* rowptr = (int*)alloc((NN + 1) * 4);
  int* cursor = (int*)alloc(NN * 4);
  int* counts = (int*)alloc(NN * 4);
  float* als1 = (float*)alloc(NN * 4);
  float* ald1 = (float*)alloc(NN * 4);
  float* als2 = (float*)alloc(NN * 4);
  float* ald2 = (float*)alloc(NN * 4);
  float* ps1  = (float*)alloc(1024 * 4);
  float* pd1  = (float*)alloc(1024 * 4);
  float* ps2  = (float*)alloc(1024 * 4);
  float* pd2  = (float*)alloc(1024 * 4);
  int* eflag  = (int*)alloc(256);
  // interior arena usage ~85 MB < 163.84 MB  ✓

  off = ((size_t)NN * CC1P * 2 + 255) & ~(size_t)255;
  u16* h2 = (u16*)alloc((size_t)NN * HH2 * 2);       // agg2 -> FC1
  u16* h4 = h2;                                       // FC2 -> FC3 (time-disjoint)
  u16* Bf = (u16*)alloc((size_t)HH2 * CC1P * 2);     // JIT-shared weight slab
  float* bsum   = (float*)alloc((size_t)CC1 * 2 * 4);
  float* bsumsq = bsum + CC1;                         // FIXED offset CC1 — always
  float* bmu    = (float*)alloc((size_t)CC1 * 4);
  float* brs    = (float*)alloc((size_t)CC1 * 4);

  // x -> bf16
  k_f32_to_bf16<<<CEILDIV(NN * DD, 256), 256, 0, stream>>>(x, xb, NN * DD);

  // edge dtype detect + CSR (shared by both GAT layers)
  k_detect_e64<<<1, 256, 0, stream>>>(ei, eflag);
  k_zero32<<<CEILDIV(NN, 256), 256, 0, stream>>>((unsigned int*)counts, NN);
  k_edge_count<<<CEILDIV(EA, 256), 256, 0, stream>>>(ei, eflag, counts);
  k_scan<<<1, 1024, 0, stream>>>(counts, rowptr, cursor, NN);
  k_edge_fill<<<CEILDIV(EA, 256), 256, 0, stream>>>(ei, eflag, cursor, esrc);

  // ---- GAT layer 1 ----
  k_convT<<<dim3(CEILDIV(HH1, 32), CEILDIV(DD, 32)), 256, 0, stream>>>(g1Ws, Bt1, DD, HH1, DD);
  k_proj_vec<<<DD, 64, 0, stream>>>(g1Ws, g1as, g1Wd, g1ad, ps1, pd1, DD, HH1);
  k_attn_logits<<<NN, 64, 0, stream>>>(xb, ps1, pd1, als1, ald1, DD);
  k_mfma_gemm<false, false><<<CEILDIV(HH1, 128) * CEILDIV(NN, 128), 256, 0, stream>>>(
      xb, Bt1, nullptr, xs1, NN, HH1, DD, HH1, CEILDIV(HH1, 128), nullptr, nullptr);
  k_gat_aggregate<1><<<NN, 256, 0, stream>>>(rowptr, esrc, als1, ald1, xs1, g1b, h1, HH1);

  // ---- GAT layer 2 ----
  k_convT<<<dim3(CEILDIV(HH2, 32), CEILDIV(HH1, 32)), 256, 0, stream>>>(g2Ws, Bt2, HH1, HH2, HH1);
  k_proj_vec<<<HH1, 64, 0, stream>>>(g2Ws, g2as, g2Wd, g2ad, ps2, pd2, HH1, HH2);
  k_attn_logits<<<NN, 64, 0, stream>>>(h1, ps2, pd2, als2, ald2, HH1);
  k_mfma_gemm<false, false><<<CEILDIV(HH2, 128) * CEILDIV(NN, 128), 256, 0, stream>>>(
      h1, Bt2, nullptr, xs2, NN, HH2, HH1, HH2, CEILDIV(HH2, 128), nullptr, nullptr);
  k_gat_aggregate<4><<<NN, 256, 0, stream>>>(rowptr, esrc, als2, ald2, xs2, g2b, h2, HH2);

  // ---- FC1 + BN1 + ReLU ----  (stats fused into GEMM epilogue; full 2*CC1 clear)
  k_convT<<<dim3(CEILDIV(CC1, 32), CEILDIV(HH2, 32)), 256, 0, stream>>>(f1W, Bf, HH2, CC1, HH2);
  k_zero32<<<CEILDIV(2 * CC1, 256), 256, 0, stream>>>((unsigned int*)bsum, 2 * CC1);
  k_mfma_gemm<true, true><<<CEILDIV(CC1, 128) * CEILDIV(NN, 128), 256, 0, stream>>>(
      h2, Bf, f1b, h3, NN, CC1, HH2, CC1P, CEILDIV(CC1, 128), bsum, bsumsq);
  k_bn_finalize<<<CEILDIV(CC1, 256), 256, 0, stream>>>(bsum, bsumsq, bmu, brs, CC1, 1.f / NN);
  k_bn_apply_relu<<<CEILDIV((long)NN * CC1 / 4, 256), 256, 0, stream>>>(
      h3, bmu, brs, bn1g, bn1b, (long)NN * CC1 / 4, CC1, CC1P);

  // ---- FC2 + BN2 + ReLU ----  (K padded to 4096)
  k_convT<<<dim3(CEILDIV(HH2, 32), CEILDIV(CC1P, 32)), 256, 0, stream>>>(f2W, Bf, CC1, HH2, CC1P);
  k_zero32<<<CEILDIV(2 * CC1, 256), 256, 0, stream>>>((unsigned int*)bsum, 2 * CC1);
  k_mfma_gemm<true, true><<<CEILDIV(HH2, 128) * CEILDIV(NN, 128), 256, 0, stream>>>(
      h3, Bf, f2b_, h4, NN, HH2, CC1P, HH2, CEILDIV(HH2, 128), bsum, bsumsq);
  k_bn_finalize<<<CEILDIV(HH2, 256), 256, 0, stream>>>(bsum, bsumsq, bmu, brs, HH2, 1.f / NN);
  k_bn_apply_relu<<<CEILDIV((long)NN * HH2 / 4, 256), 256, 0, stream>>>(
      h4, bmu, brs, bn2g, bn2b, (long)NN * HH2 / 4, HH2, HH2);

  // ---- FC3 + BN3 + ReLU ----  (h5 in arena A; h3 dead)
  k_convT<<<dim3(CEILDIV(HH1, 32), CEILDIV(HH2, 32)), 256, 0, stream>>>(f3W, Bf, HH2, HH1, HH2);
  k_zero32<<<CEILDIV(2 * CC1, 256), 256, 0, stream>>>((unsigned int*)bsum, 2 * CC1);
  k_mfma_gemm<true, true><<<CEILDIV(HH1, 128) * CEILDIV(NN, 128), 256, 0, stream>>>(
      h4, Bf, f3b, h5, NN, HH1, HH2, HH1, CEILDIV(HH1, 128), bsum, bsumsq);
  k_bn_finalize<<<CEILDIV(HH1, 256), 256, 0, stream>>>(bsum, bsumsq, bmu, brs, HH1, 1.f / NN);
  k_bn_apply_relu<<<CEILDIV((long)NN * HH1 / 4, 256), 256, 0, stream>>>(
      h5, bmu, brs, bn3g, bn3b, (long)NN * HH1 / 4, HH1, HH1);

  // ---- FC4 + log_softmax ----
  k_fc4_logsoftmax<<<NN, 64, 0, stream>>>(h5, f4W, f4b, out);
}